// Round 8
// baseline (121.266 us; speedup 1.0000x reference)
//
#include <hip/hip_runtime.h>
#include <stdint.h>
#include <stddef.h>

// Problem: out[b][o] = sum_{i,g} spline(x[b][i])[g] * coef[o][i][g]
//   x: (4096, 1024) f32; coef: (1024, 1024, 8) f32; out: (4096, 1024) f32
// == GEMM: A (4096 x 8192) * B^T (1024 x 8192), K = i*8+g.
//
// R8 change: WAVE TILE 128x64 -> 128x128 (4 waves/block, 2x2, 256 thr,
// 1 wave/SIMD). Same 256x256 block tile, same LDS layout/volume, same
// R0 4-window trailing-read schedule; per-wave LDS reads per K64 go
// 24KB->32KB for 2x FLOPs = -33% LDS-read traffic per tile (192->128
// ds_read_b128/CU/tile). LDS unit is the measured bottleneck (~70% util
// at R0's 4290 cyc/tile); traffic cut targets it directly. Staging
// per-wave doubles (16 gloads/tile) -> counted vmcnt(8). acc 256 AGPR +
// 96 VGPR operands fits 1 wave/SIMD (launch_bounds(256,1)).
// Split s=0 writes C f32; s>0 write bf16 partials; reduce kernel sums.

#define BATCH 4096
#define IN    1024
#define OUTN  1024
#define KDIM  (IN * 8)     // 8192
#define NTT   (KDIM / 64)  // 128 K-tiles of BK=64

typedef __attribute__((ext_vector_type(8)))  short          short8;
typedef __attribute__((ext_vector_type(8)))  unsigned short ushort8;
typedef __attribute__((ext_vector_type(4)))  float          f32x4;

// ---------- helpers ----------

__device__ __forceinline__ constexpr float Cf(int i) {
    constexpr double end  = 1.0 + 2.0 * 4.0 / 7.0;        // 1 + 8/7
    constexpr double step = (end - (-1.0)) / 11.0;
    return (float)(-1.0 + (double)i * step);
}

__device__ __forceinline__ unsigned short f2bf(float f) {
    unsigned int u = __builtin_bit_cast(unsigned int, f);
    u += 0x7fffu + ((u >> 16) & 1u);      // round-to-nearest-even
    return (unsigned short)(u >> 16);
}

__device__ __forceinline__ float bf2f(unsigned short u) {
    unsigned int v = (unsigned int)u << 16;
    return __builtin_bit_cast(float, v);
}

__device__ __forceinline__ ushort8 spline8(float xt) {
    float v[11];
#pragma unroll
    for (int j = 0; j < 11; ++j)
        v[j] = (xt >= Cf(j) && xt < Cf(j + 1)) ? 1.0f : 0.0f;
#pragma unroll
    for (int k = 1; k <= 3; ++k) {
#pragma unroll
        for (int j = 0; j < 11 - k; ++j) {
            float left  = (xt - Cf(j))         * (1.0f / (Cf(j + k)     - Cf(j)));
            float right = (Cf(j + k + 1) - xt) * (1.0f / (Cf(j + k + 1) - Cf(j + 1)));
            v[j] = left * v[j] + right * v[j + 1];
        }
    }
    ushort8 r;
#pragma unroll
    for (int g = 0; g < 8; ++g) r[g] = f2bf(v[g]);
    return r;
}

typedef const unsigned int __attribute__((address_space(1))) gu32;
typedef unsigned int       __attribute__((address_space(3))) lu32;

__device__ __forceinline__ void gload_lds16(const void* g, void* l) {
    __builtin_amdgcn_global_load_lds((gu32*)g, (lu32*)l, 16, 0, 0);
}

// ---------- kernel 1: fused prep -> A_shuf / B_shuf fragment images ----------
//
// 16x16x32 frag map: row = lane&15, k = kb*32 + (lane>>4)*8 + e.
// Image (ushort8 units): [rg=row>>4][kb=k>>5][lane][e].
// Element (row, i, g): kb = i>>2, lane = (i&3)*16 + (row&15), e = g.

__global__ void prep_kernel(const float* __restrict__ x, const float* __restrict__ coef,
                            unsigned short* __restrict__ A, unsigned short* __restrict__ B) {
    const int t = threadIdx.x;
    int blk = blockIdx.x;
    if (blk < 4096) {
        // basis: 256 bb x 16 bi blocks; row = b
        const int bb = blk >> 4, bi = blk & 15;
        const int b  = bb * 16 + (t & 15);
        const int i0 = bi * 64 + (t >> 4) * 4;
        f32x4 xv = *reinterpret_cast<const f32x4*>(&x[(size_t)b * IN + i0]);
        ushort8 r[4];
#pragma unroll
        for (int j = 0; j < 4; ++j) r[j] = spline8(tanhf(xv[j]));
        ushort8* out = reinterpret_cast<ushort8*>(A)
                     + ((size_t)(bb * 256 + bi * 16 + (t >> 4)) * 64) + (t & 15);
        out[0]  = r[0];
        out[16] = r[1];
        out[32] = r[2];
        out[48] = r[3];
    } else {
        // coef cvt: 64 ob x 16 ib blocks; row = o
        blk -= 4096;
        const int ob = blk >> 4, ib = blk & 15;
        const int oo = ob * 16 + (t & 15);
        const int i0 = ib * 64 + (t >> 4) * 4;
        const f32x4* cin = reinterpret_cast<const f32x4*>(coef);
        ushort8 r[4];
#pragma unroll
        for (int j = 0; j < 4; ++j) {
            f32x4 v0 = cin[((size_t)oo * IN + i0 + j) * 2];
            f32x4 v1 = cin[((size_t)oo * IN + i0 + j) * 2 + 1];
#pragma unroll
            for (int g = 0; g < 4; ++g) { r[j][g] = f2bf(v0[g]); r[j][4 + g] = f2bf(v1[g]); }
        }
        ushort8* out = reinterpret_cast<ushort8*>(B)
                     + ((size_t)(ob * 256 + ib * 16 + (t >> 4)) * 64) + (t & 15);
        out[0]  = r[0];
        out[16] = r[1];
        out[32] = r[2];
        out[48] = r[3];
    }
}

// ---------- kernel 2: 256x256 bf16 GEMM, 4 waves x 128x128, R0 windows ----------
//
// Waves 2x2 (wm=w>>1 rows, wn=w&1 cols); per-wave output 128x128:
// acc[8 mf][8 nf] f32x4 (256 AGPR). LDS per buf: A 32 slots (rg*2+kk) x 1KB,
// B same; slot(rg,kk) = rg*2+kk.
// Windows per tile t (buf c = t%2, n = other); MFMA first (pre-read
// operands), reads/stages trail (R0 discipline, counts x2):
//  W1: BAR; Q(0,0)[aF=H0(t),bv0(t): read W4(t-1)]; read bv1(t); stage B1,A1(t+1)->n (8gl)
//  W2: BAR; Q(0,1)[aF,bv1]; read H1(t)->aF; stage B0(t+2)->c (4gl)
//  W3: BAR; Q(1,0)[aF,bv0]; stage A0(t+2)->c (4gl); vmcnt(8)
//  W4: BAR(publish t+1); Q(1,1)[aF,bv1]; read H0(t+1)->aF, bv0(t+1) from n
// Events/wave/tile = 16. At W3: outstanding = [W2(t-1):4][W3(t-1):4]
// [W1:8][W2:4][W3:4] = 24 -> vmcnt(8) retires 16 oldest = ALL of t+1's
// halves, leaves B0/A0(t+2)'s 8. Slot-reuse: every slot's last ds_read
// completed (lgkm-consumed by an MFMA) >=1 barrier before its re-stage.

#define LSA0 (&Ls[0][0])
#define LSB0 (&Ls[0][16384])
#define LSA1 (&Ls[1][0])
#define LSB1 (&Ls[1][16384])

template<int NSPLIT>
__global__ __launch_bounds__(256, 1) void gemm_bt(
        const unsigned short* __restrict__ Ashuf,  // [256 rg][256 kb][64][8]
        const unsigned short* __restrict__ Bshuf,  // [64 cg][256 kb][64][8]
        float* __restrict__ C,                     // [4096][1024]
        unsigned short* __restrict__ P) {          // bf16 partials (splits 1..)
    constexpr int NT2 = NTT / NSPLIT;              // K-tiles per block
    static_assert((NT2 & 1) == 0 && NT2 >= 8, "loop assumes even NT2 >= 8");
    __shared__ unsigned short Ls[2][32768];        // 128 KiB

    const int tid  = threadIdx.x;
    const int w    = tid >> 6;                     // 0..3
    const int lane = tid & 63;
    const int wm   = w >> 1, wn = w & 1;
    const int lane8 = lane * 8;

    const int bid  = blockIdx.x;
    const int s    = bid & (NSPLIT - 1);
    const int tile = bid / NSPLIT;                 // 0..63
    const int mb16 = (tile >> 2) * 16;             // A rg base
    const int nb16 = (tile & 3) * 16;              // B cg base
    const int T0   = s * NT2;
    const int brow = mb16 * 16, bcol = nb16 * 16;

    // Stage half H (8 rg x 2 kk = 16 slots): wave w covers slots w*4..w*4+3.
    // slot = H*16 + w*4 + j -> local rg = H*8 + w*2 + (j>>1), kk = j&1.
#define STAGE_OP(BASE, NB16, H, T, LS) do {                                   \
        _Pragma("unroll")                                                     \
        for (int j = 0; j < 4; ++j) {                                         \
            const int _rg = (H)*8 + w*2 + (j >> 1);                           \
            const int _kk = j & 1;                                            \
            const unsigned short* _g = (BASE)                                 \
                + ((size_t)((NB16) + _rg) << 17)                              \
                + ((size_t)(2 * (T0 + (T)) + _kk)) * 512 + lane8;             \
            unsigned short* _l = (LS) + ((_rg * 2 + _kk) << 9);               \
            gload_lds16(_g, _l);                                              \
        }                                                                     \
    } while (0)
#define STAGE_A(H, T, LS) STAGE_OP(Ashuf, mb16, H, T, LS)
#define STAGE_B(H, T, LS) STAGE_OP(Bshuf, nb16, H, T, LS)

    // read aF for row-half H: 8 x ds_read_b128 (rg = wm*8 + H*4 + i)
#define LDA_F(DST, H, LS) do {                                                \
        _Pragma("unroll")                                                     \
        for (int i = 0; i < 4; ++i)                                           \
            _Pragma("unroll")                                                 \
            for (int kk = 0; kk < 2; ++kk)                                    \
                DST[i][kk] = *reinterpret_cast<const short8*>(                \
                    (LS) + (((wm*8 + (H)*4 + i) * 2 + kk) << 9) + lane8);     \
    } while (0)
    // read bv for col-half V: 8 x ds_read_b128 (cg = wn*8 + V*4 + j)
#define LDB_F(DST, V, LS) do {                                                \
        _Pragma("unroll")                                                     \
        for (int j = 0; j < 4; ++j)                                           \
            _Pragma("unroll")                                                 \
            for (int kk = 0; kk < 2; ++kk)                                    \
                DST[j][kk] = *reinterpret_cast<const short8*>(                \
                    (LS) + (((wn*8 + (V)*4 + j) * 2 + kk) << 9) + lane8);     \
    } while (0)

    f32x4 acc[8][8] = {};                          // [H*4+i][V*4+j], 256 AGPR
    short8 aF[4][2], bv0[4][2], bv1[4][2];

    // window (H,V): 32 MFMA (16 indep chains per kk)
#define MFMA_Q(H, V, BV) do {                                                 \
        __builtin_amdgcn_s_setprio(1);                                        \
        _Pragma("unroll")                                                     \
        for (int kk = 0; kk < 2; ++kk)                                        \
            _Pragma("unroll")                                                 \
            for (int i = 0; i < 4; ++i)                                       \
                _Pragma("unroll")                                             \
                for (int j = 0; j < 4; ++j)                                   \
                    acc[(H)*4 + i][(V)*4 + j] =                               \
                        __builtin_amdgcn_mfma_f32_16x16x32_bf16(              \
                            aF[i][kk], BV[j][kk],                             \
                            acc[(H)*4 + i][(V)*4 + j], 0, 0, 0);              \
        __builtin_amdgcn_s_setprio(0);                                        \
    } while (0)

    // Pipelined tile: MFMA first (pre-read operands), reads/stages trail.
#define TILE(T, LAC, LBC, LAN, LBN, S1F, S23F, RN, VC) do {                   \
        __builtin_amdgcn_s_barrier();                                         \
        MFMA_Q(0, 0, bv0);                                                    \
        LDB_F(bv1, 1, LBC);                                                   \
        if (S1F) { STAGE_B(1, (T) + 1, LBN); STAGE_A(1, (T) + 1, LAN); }      \
        __builtin_amdgcn_s_barrier();                                         \
        MFMA_Q(0, 1, bv1);                                                    \
        LDA_F(aF, 1, LAC);                                                    \
        if (S23F) STAGE_B(0, (T) + 2, LBC);                                   \
        __builtin_amdgcn_s_barrier();                                         \
        MFMA_Q(1, 0, bv0);                                                    \
        if (S23F) STAGE_A(0, (T) + 2, LAC);                                   \
        asm volatile("s_waitcnt vmcnt(" VC ")" ::: "memory");                 \
        __builtin_amdgcn_s_barrier();                                         \
        MFMA_Q(1, 1, bv1);                                                    \
        if (RN) { LDA_F(aF, 0, LAN); LDB_F(bv0, 0, LBN); }                    \
    } while (0)

    // prologue: 24 gloads (tile0's 4 halves + tile1's B0/A0); vmcnt(8)
    // retires tile0's 16; publish; pre-read tile0's H0/bv0.
    STAGE_B(0, 0, LSB0); STAGE_A(0, 0, LSA0);
    STAGE_B(1, 0, LSB0); STAGE_A(1, 0, LSA0);
    STAGE_B(0, 1, LSB1); STAGE_A(0, 1, LSA1);
    asm volatile("s_waitcnt vmcnt(8)" ::: "memory");
    __builtin_amdgcn_s_barrier();
    LDA_F(aF, 0, LSA0); LDB_F(bv0, 0, LSB0);

#pragma unroll 1
    for (int t = 0; t + 2 <= NT2 - 2; t += 2) {
        TILE(t,     LSA0, LSB0, LSA1, LSB1, 1, 1, 1, "8");
        TILE(t + 1, LSA1, LSB1, LSA0, LSB0, 1, 1, 1, "8");
    }
    // tail: NT2-2 stages B1,A1(NT2-1) only; W3 outstanding = 16 -> vmcnt(0)
    // retires all before W4's pre-reads. NT2-1: no stages, no pre-reads.
    TILE(NT2 - 2, LSA0, LSB0, LSA1, LSB1, 1, 0, 1, "0");
    TILE(NT2 - 1, LSA1, LSB1, LSA0, LSB0, 0, 0, 0, "0");

    // epilogue: C/D layout col=lane&15, row=(lane>>4)*4+reg (m89-verified)
    // s==0 -> f32 to C; s>0 -> bf16 partial slab (reduce kernel sums).
    const int q4 = (lane >> 4) * 4, frow = lane & 15;
    if (NSPLIT == 1 || s == 0) {
#pragma unroll
        for (int mf = 0; mf < 8; ++mf)
#pragma unroll
            for (int nf = 0; nf < 8; ++nf)
#pragma unroll
                for (int r = 0; r < 4; ++r) {
                    int row = brow + wm * 128 + mf * 16 + q4 + r;
                    int col = bcol + wn * 128 + nf * 16 + frow;
                    C[(size_t)row * OUTN + col] = acc[mf][nf][r];
                }
    } else {
        unsigned short* Pb = P + (size_t)(s - 1) * BATCH * OUTN;
#pragma unroll
        for (int mf = 0; mf < 8; ++mf)
#pragma unroll
            for (int nf = 0; nf < 8; ++nf)
#pragma unroll
                for (int r = 0; r < 4; ++r) {
                    int row = brow + wm * 128 + mf * 16 + q4 + r;
                    int col = bcol + wn * 128 + nf * 16 + frow;
                    Pb[(size_t)row * OUTN + col] = f2bf(acc[mf][nf][r]);
                }
    }
}

// ---------- kernel 3: C += sum of np bf16 partials ----------

__global__ void reduce_kernel(float* __restrict__ C, const unsigned short* __restrict__ P,
                              int np) {
    int i = blockIdx.x * 256 + threadIdx.x;        // 524,288 threads x 8 f32
    size_t base = (size_t)i * 8;
    f32x4 c0 = *reinterpret_cast<f32x4*>(&C[base]);
    f32x4 c1 = *reinterpret_cast<f32x4*>(&C[base + 4]);
    for (int j = 0; j < np; ++j) {
        ushort8 p = *reinterpret_cast<const ushort8*>(&P[(size_t)j * BATCH * OUTN + base]);
#pragma unroll
        for (int e = 0; e < 4; ++e) c0[e] += bf2f(p[e]);
#pragma unroll
        for (int e = 0; e < 4; ++e) c1[e] += bf2f(p[4 + e]);
    }
    *reinterpret_cast<f32x4*>(&C[base])     = c0;
    *reinterpret_cast<f32x4*>(&C[base + 4]) = c1;
}

// ---------- launch ----------

extern "C" void kernel_launch(void* const* d_in, const int* in_sizes, int n_in,
                              void* d_out, int out_size, void* d_ws, size_t ws_size,
                              hipStream_t stream) {
    const float* x    = (const float*)d_in[0];
    const float* coef = (const float*)d_in[1];
    float* out = (float*)d_out;

    // ws: [A_shuf 64 MiB][B_shuf 16 MiB][bf16 partials 8 MiB x (NSPLIT-1)]
    unsigned short* ashuf = (unsigned short*)d_ws;
    unsigned short* bshuf = ashuf + (size_t)BATCH * KDIM;
    unsigned short* part  = bshuf + (size_t)OUTN * KDIM;
    const size_t base = (size_t)BATCH * KDIM * 2 + (size_t)OUTN * KDIM * 2;  // 80 MiB
    const size_t slab = (size_t)BATCH * OUTN * 2;                            // 8 MiB

    prep_kernel<<<5120, 256, 0, stream>>>(x, coef, ashuf, bshuf);

    if (ws_size >= base + 3 * slab) {
        gemm_bt<4><<<256, 256, 0, stream>>>(ashuf, bshuf, out, part);
        reduce_kernel<<<2048, 256, 0, stream>>>(out, part, 3);
    } else if (ws_size >= base + slab) {
        gemm_bt<2><<<128, 256, 0, stream>>>(ashuf, bshuf, out, part);
        reduce_kernel<<<2048, 256, 0, stream>>>(out, part, 1);
    } else {
        gemm_bt<1><<<64, 256, 0, stream>>>(ashuf, bshuf, out, nullptr);
    }
}